// Round 9
// baseline (424.383 us; speedup 1.0000x reference)
//
#include <hip/hip_runtime.h>

typedef short bf16x8 __attribute__((ext_vector_type(8)));
typedef float f32x4  __attribute__((ext_vector_type(4)));
typedef unsigned int uint32;

#define M_ROWS 131072
#define N_COLS 512
#define K_DIM  64
#define MT     4

#define MFMA16 __builtin_amdgcn_mfma_f32_16x16x32_bf16

__device__ __forceinline__ short f2bf(float f) {
  return (short)(__builtin_bit_cast(uint32, f) >> 16);
}

// 0.5*tanh(p) = 0.5 - 1/(exp2(p*2*log2 e)+1); exact at 0, saturates correctly.
__device__ __forceinline__ float half_tanh(float p) {
  float t = __builtin_amdgcn_exp2f(p * 2.8853900817779268f);
  return 0.5f - __builtin_amdgcn_rcpf(t + 1.0f);
}

// Split 8 consecutive floats into bf16 hi (truncated) + bf16 lo (residual).
__device__ __forceinline__ void cvt8(const float* __restrict__ p, bf16x8& hi, bf16x8& lo) {
  f32x4 a = *(const f32x4*)p;
  f32x4 b = *(const f32x4*)(p + 4);
#pragma unroll
  for (int j = 0; j < 4; ++j) {
    uint32 ua = __builtin_bit_cast(uint32, a[j]);
    uint32 ha = ua & 0xffff0000u;
    hi[j] = (short)(ha >> 16);
    lo[j] = f2bf(a[j] - __builtin_bit_cast(float, ha));
    uint32 ub = __builtin_bit_cast(uint32, b[j]);
    uint32 hb = ub & 0xffff0000u;
    hi[4 + j] = (short)(hb >> 16);
    lo[4 + j] = f2bf(b[j] - __builtin_bit_cast(float, hb));
  }
}

__global__ __launch_bounds__(512, 2) void esn_k(const float* __restrict__ x,
                                                const float* __restrict__ w,
                                                float* __restrict__ out) {
  const int tid  = threadIdx.x;
  const int wv   = tid >> 6;
  const int lane = tid & 63;
  const int i16  = lane & 15;
  const int g    = lane >> 4;
  const int mb0  = blockIdx.x * (16 * MT);
  const f32x4 z  = {0.f, 0.f, 0.f, 0.f};
  const short ONE = (short)0x3F80;

  // ===== Probe 1: A<->B k-range alignment (confirmed non-identity in R8) =====
  bf16x8 bgv;
#pragma unroll
  for (int j = 0; j < 8; ++j) bgv[j] = f2bf((float)(g + 1));
  int pig[4];
  bool okp = true;
#pragma unroll
  for (int g0 = 0; g0 < 4; ++g0) {
    bf16x8 dA;
#pragma unroll
    for (int j = 0; j < 8; ++j) dA[j] = (g == g0) ? ONE : (short)0;
    f32x4 dt = MFMA16(dA, bgv, z, 0, 0, 0);
    int v = (int)(dt[0] * 0.125f + 0.5f);
    bool u = (v >= 1) && (v <= 4);
#pragma unroll
    for (int q = 0; q < 4; ++q) u = u && (fabsf(dt[q] - 8.f * (float)v) < 1e-3f);
    okp = okp && u;
    pig[g0] = v - 1;
  }
  okp = okp && (((1 << pig[0]) | (1 << pig[1]) | (1 << pig[2]) | (1 << pig[3])) == 15);
  int pinv_g = 0;
#pragma unroll
  for (int g0 = 0; g0 < 4; ++g0) if (pig[g0] == g) pinv_g = g0;

  // ===== Probe 2: row/col decode =====
  bf16x8 ones, vals;
#pragma unroll
  for (int j = 0; j < 8; ++j) { ones[j] = ONE; vals[j] = f2bf((float)i16); }
  f32x4 d1 = MFMA16(vals, ones, z, 0, 0, 0);
  f32x4 d2 = MFMA16(ones, vals, z, 0, 0, 0);
  int rowv[4], colv[4];
  bool ok = okp;
#pragma unroll
  for (int q = 0; q < 4; ++q) {
    rowv[q] = (int)(d1[q] * 0.03125f + 0.5f);
    colv[q] = (int)(d2[q] * 0.03125f + 0.5f);
    ok = ok && (rowv[q] >= 0) && (rowv[q] < 16) && (colv[q] >= 0) && (colv[q] < 16);
  }

  // ===== Probe 3: strict 32-periodic numeric test with remapped B =====
  bf16x8 ta, tb;
#pragma unroll
  for (int j = 0; j < 8; ++j) {
    const int ka = 8 * g + j;
    const int kb = 8 * pinv_g + j;
    ta[j] = f2bf(0.25f + (float)((5 * i16 + 3 * ka) & 31) * 0.03125f);
    tb[j] = f2bf(0.25f + (float)((7 * kb + 11 * i16) & 31) * 0.03125f);
  }
  f32x4 dt3 = MFMA16(ta, tb, z, 0, 0, 0);
#pragma unroll
  for (int q = 0; q < 4; ++q) {
    float ref = 0.f;
    for (int k = 0; k < 32; ++k) {
      const float av = 0.25f + (float)((5 * rowv[q] + 3 * k) & 31) * 0.03125f;
      const float bv = 0.25f + (float)((7 * k + 11 * colv[q]) & 31) * 0.03125f;
      ref = fmaf(av, bv, ref);
    }
    ok = ok && (fabsf(dt3[q] - ref) < 1e-3f);
  }
  const bool probes_ok = __all((int)ok);
  const bool vec = probes_ok &&
      __all((int)(colv[0] == colv[1] && colv[1] == colv[2] && colv[2] == colv[3] &&
                  rowv[1] == rowv[0] + 1 && rowv[2] == rowv[0] + 2 &&
                  rowv[3] == rowv[0] + 3 && (rowv[0] & 3) == 0));

  bool mfma_good = false;

  if (probes_ok) {
    // ---- per-lane sample cells: wave covers all 64 (t,q,mi) cells, 2x each ----
    const int t_s0 = i16 & 3,        t_s1 = 3 - t_s0;
    const int q_s0 = g,              q_s1 = 3 - g;
    const int mi_s0 = i16 >> 2,      mi_s1 = 3 - mi_s0;
    float av0 = 0.f, av1 = 0.f;

    // w fragments: 4 r-tiles x hi/lo x 2 k-frags
    bf16x8 wh[4][2], wl[4][2];
#pragma unroll
    for (int t = 0; t < 4; ++t) {
      const float* wb = w + (size_t)(64 * wv + 16 * t + i16) * K_DIM + 8 * g;
      cvt8(wb, wh[t][0], wl[t][0]);
      cvt8(wb + 32, wh[t][1], wl[t][1]);
    }

#pragma unroll 1
    for (int mi = 0; mi < MT; ++mi) {
      const int mb = mb0 + 16 * mi;
      const float* xb = x + (size_t)(mb + i16) * K_DIM + 8 * pinv_g;
      bf16x8 xh[2], xl[2];
      cvt8(xb, xh[0], xl[0]);
      cvt8(xb + 32, xh[1], xl[1]);

      f32x4 acc[4];
#pragma unroll
      for (int t = 0; t < 4; ++t) {
        acc[t] = z;
#pragma unroll
        for (int kf = 0; kf < 2; ++kf) {
          acc[t] = MFMA16(wh[t][kf], xh[kf], acc[t], 0, 0, 0);
          acc[t] = MFMA16(wh[t][kf], xl[kf], acc[t], 0, 0, 0);
          acc[t] = MFMA16(wl[t][kf], xh[kf], acc[t], 0, 0, 0);
          acc[t] = MFMA16(wl[t][kf], xl[kf], acc[t], 0, 0, 0);
        }
      }

      // grab sampled accumulator values (static indexing only)
#pragma unroll
      for (int t = 0; t < 4; ++t)
#pragma unroll
        for (int q = 0; q < 4; ++q) {
          const float a = acc[t][q];
          av0 = (mi == mi_s0 && t == t_s0 && q == q_s0) ? a : av0;
          av1 = (mi == mi_s1 && t == t_s1 && q == q_s1) ? a : av1;
        }

      // optimistic store (fallback overwrites the whole region on failure)
#pragma unroll
      for (int t = 0; t < 4; ++t) {
        const int rbase = 64 * wv + 16 * t;
        if (vec) {
          f32x4 v;
#pragma unroll
          for (int q = 0; q < 4; ++q) v[q] = half_tanh(acc[t][q]);
          *(f32x4*)(out + (size_t)(mb + colv[0]) * N_COLS + rbase + rowv[0]) = v;
        } else {
#pragma unroll
          for (int q = 0; q < 4; ++q)
            out[(size_t)(mb + colv[q]) * N_COLS + rbase + rowv[q]] = half_tanh(acc[t][q]);
        }
      }
    }

    // ---- verify the 2 sampled cells against full-f32 VALU dots ----
    int rw0 = 0, cl0 = 0, rw1 = 0, cl1 = 0;
#pragma unroll
    for (int q = 0; q < 4; ++q) {
      rw0 = (q == q_s0) ? rowv[q] : rw0;  cl0 = (q == q_s0) ? colv[q] : cl0;
      rw1 = (q == q_s1) ? rowv[q] : rw1;  cl1 = (q == q_s1) ? colv[q] : cl1;
    }
    const float* ws0 = w + (size_t)(64 * wv + 16 * t_s0 + rw0) * K_DIM;
    const float* xs0 = x + (size_t)(mb0 + 16 * mi_s0 + cl0) * K_DIM;
    const float* ws1 = w + (size_t)(64 * wv + 16 * t_s1 + rw1) * K_DIM;
    const float* xs1 = x + (size_t)(mb0 + 16 * mi_s1 + cl1) * K_DIM;
    float dot0 = 0.f, dab0 = 0.f, dot1 = 0.f, dab1 = 0.f;
#pragma unroll 8
    for (int k = 0; k < K_DIM; ++k) {
      dot0 = fmaf(ws0[k], xs0[k], dot0);
      dab0 = fmaf(fabsf(ws0[k]), fabsf(xs0[k]), dab0);
      dot1 = fmaf(ws1[k], xs1[k], dot1);
      dab1 = fmaf(fabsf(ws1[k]), fabsf(xs1[k]), dab1);
    }
    const bool sok = (fabsf(dot0 - av0) <= 1e-3f + 3e-4f * dab0) &&
                     (fabsf(dot1 - av1) <= 1e-3f + 3e-4f * dab1);
    mfma_good = __all((int)sok);
  }

  if (!mfma_good) {
    // ---------- VALU fallback: overwrite this wave's entire region ----------
    const int r = 64 * wv + lane;
    f32x4 wr[16];
    const f32x4* wp = (const f32x4*)(w + (size_t)r * K_DIM);
#pragma unroll
    for (int i = 0; i < 16; ++i) wr[i] = wp[i];

    const f32x4* xrow = (const f32x4*)(x + (size_t)mb0 * K_DIM);
    float* orow = out + (size_t)mb0 * N_COLS + r;
#pragma unroll 1
    for (int mi = 0; mi < 16 * MT; ++mi) {
      const f32x4* xq = xrow + (size_t)mi * 16;
      f32x4 acc = z;
#pragma unroll
      for (int kc = 0; kc < 16; kc += 4)
#pragma unroll
        for (int j = 0; j < 4; ++j) {
          acc[0] = fmaf(xq[kc + 0][j], wr[kc + 0][j], acc[0]);
          acc[1] = fmaf(xq[kc + 1][j], wr[kc + 1][j], acc[1]);
          acc[2] = fmaf(xq[kc + 2][j], wr[kc + 2][j], acc[2]);
          acc[3] = fmaf(xq[kc + 3][j], wr[kc + 3][j], acc[3]);
        }
      orow[(size_t)mi * N_COLS] = half_tanh((acc[0] + acc[1]) + (acc[2] + acc[3]));
    }
  }
}

extern "C" void kernel_launch(void* const* d_in, const int* in_sizes, int n_in,
                              void* d_out, int out_size, void* d_ws, size_t ws_size,
                              hipStream_t stream) {
  const float* x = (const float*)d_in[0];   // [131072, 64]
  const float* w = (const float*)d_in[1];   // [512, 64]
  // d_in[2] (d) is dead: reference state is identically zero.
  float* out = (float*)d_out;               // [131072, 512]

  dim3 grid(M_ROWS / (16 * MT));   // 2048 blocks, 64 m-rows each
  dim3 block(512);                 // 8 waves; wave w -> r in [64w, 64w+64)
  hipLaunchKernelGGL(esn_k, grid, block, 0, stream, x, w, out);
}